// Round 1
// baseline (1076.608 us; speedup 1.0000x reference)
//
#include <hip/hip_runtime.h>

#define GB    16     // batches per block
#define NTOK  16
#define NSLOT 4
#define CIN   8
#define DD    32

// padded LDS strides (in floats)
#define LATROW 132
#define VROW   36
#define VBAT   (NTOK * VROW + 4)   // 580
#define SROW   36
#define SBAT   (NSLOT * SROW + 4)  // 148
#define ABAT   (NTOK * NSLOT + 4)  // 68

#define SCALE_F 0.17677669529663687f  // 32^-0.5

__device__ __forceinline__ float sigm(float x)  { return 1.0f / (1.0f + __expf(-x)); }
__device__ __forceinline__ float tanhf_(float x){ return 1.0f - 2.0f / (__expf(2.0f * x) + 1.0f); }

__global__ __launch_bounds__(256, 2)
void slotattn_kernel(const float* __restrict__ latent,
                     const float* __restrict__ slot_mu,
                     const float* __restrict__ w_in,
                     const float* __restrict__ b_in,
                     const float* __restrict__ ln_g,
                     const float* __restrict__ ln_b,
                     const float* __restrict__ wq,
                     const float* __restrict__ wk,
                     const float* __restrict__ wv,
                     const float* __restrict__ gwih,
                     const float* __restrict__ gwhh,
                     const float* __restrict__ gbih,
                     const float* __restrict__ gbhh,
                     float* __restrict__ out)
{
    __shared__ __attribute__((aligned(16))) float lds_v[GB * VBAT];
    __shared__ __attribute__((aligned(16))) float lds_slots[GB * SBAT];
    __shared__ __attribute__((aligned(16))) float lds_q[GB * SBAT];   // overlaid: latent staging in init
    __shared__ __attribute__((aligned(16))) float lds_upd[GB * SBAT];
    __shared__ __attribute__((aligned(16))) float lds_attn[GB * ABAT];

    const int tid  = threadIdx.x;                                   // 0..255
    const int wid  = __builtin_amdgcn_readfirstlane(tid >> 6);      // wave id 0..3 (forced uniform)
    const int lane = tid & 63;
    const int tb = tid >> 4, tn = tid & 15;                         // token mapping
    const int sb = lane >> 2, ss = lane & 3;                        // slot-row mapping
    const int dlo = wid * 8;                                        // d-chunk for slot phases
    const int blockBase = blockIdx.x * GB;

    // ---- init: stage latent (coalesced) + init slots from slot_mu ----
    {
        const float* src = latent + (size_t)blockBase * (CIN * NTOK) + tid * 8;
        float4 a = *(const float4*)(src);
        float4 b = *(const float4*)(src + 4);
        int i = tid * 8;
        int lb = i >> 7, rem = i & 127;
        float* dst = lds_q + lb * LATROW + rem;
        *(float4*)(dst)     = a;
        *(float4*)(dst + 4) = b;
    }
    for (int i = tid; i < GB * NSLOT * DD; i += 256) {
        int b = i >> 7, rem = i & 127;
        lds_slots[b * SBAT + (rem >> 5) * SROW + (rem & 31)] = slot_mu[rem];
    }
    __syncthreads();

    // ---- phase 2 (token-local): x = lat@w_in.T + b -> LN -> k (regs), v (LDS) ----
    float kreg[DD];
    {
        const float* lat = lds_q + tb * LATROW + tn;
        float c[CIN];
        #pragma unroll
        for (int cc = 0; cc < CIN; ++cc) c[cc] = lat[cc * 16];
        float xr[DD];
        #pragma unroll
        for (int d = 0; d < DD; ++d) {
            float acc = b_in[d];
            #pragma unroll
            for (int cc = 0; cc < CIN; ++cc)
                acc = fmaf(c[cc], w_in[d * CIN + cc], acc);
            xr[d] = acc;
        }
        float mu = 0.f;
        #pragma unroll
        for (int d = 0; d < DD; ++d) mu += xr[d];
        mu *= (1.0f / DD);
        float var = 0.f;
        #pragma unroll
        for (int d = 0; d < DD; ++d) { float t = xr[d] - mu; var = fmaf(t, t, var); }
        var *= (1.0f / DD);
        float rs = rsqrtf(var + 1e-5f);
        #pragma unroll
        for (int d = 0; d < DD; ++d)
            xr[d] = (xr[d] - mu) * rs * ln_g[d] + ln_b[d];

        float* vdst = lds_v + tb * VBAT + tn * VROW;
        #pragma unroll 4
        for (int d = 0; d < DD; ++d) {
            float ak = 0.f, av = 0.f;
            #pragma unroll
            for (int e = 0; e < DD; ++e) {
                ak = fmaf(xr[e], wk[d * DD + e], ak);
                av = fmaf(xr[e], wv[d * DD + e], av);
            }
            kreg[d] = ak;
            vdst[d] = av;
        }
    }
    __syncthreads();

    for (int it = 0; it < 3; ++it) {
        // ---- A (slot rows x d-chunk): q = slots @ wq.T, scale folded in ----
        {
            const float* srow = lds_slots + sb * SBAT + ss * SROW;
            float h[DD];
            #pragma unroll
            for (int e = 0; e < DD; ++e) h[e] = srow[e];
            float* qdst = lds_q + sb * SBAT + ss * SROW;
            #pragma unroll 2
            for (int j = 0; j < 8; ++j) {
                int d = dlo + j;
                float acc = 0.f;
                #pragma unroll
                for (int e = 0; e < DD; ++e)
                    acc = fmaf(h[e], wq[d * DD + e], acc);
                qdst[d] = acc * SCALE_F;
            }
        }
        __syncthreads();
        // ---- B (token rows): logits = q.k (k in regs), softmax over 4 slots ----
        {
            const float* qb = lds_q + tb * SBAT;
            float l[NSLOT];
            #pragma unroll
            for (int s = 0; s < NSLOT; ++s) {
                const float* q = qb + s * SROW;
                float acc = 0.f;
                #pragma unroll
                for (int e = 0; e < DD; ++e)
                    acc = fmaf(kreg[e], q[e], acc);
                l[s] = acc;
            }
            float m  = fmaxf(fmaxf(l[0], l[1]), fmaxf(l[2], l[3]));
            float e0 = __expf(l[0] - m), e1 = __expf(l[1] - m);
            float e2 = __expf(l[2] - m), e3 = __expf(l[3] - m);
            float inv = 1.0f / (e0 + e1 + e2 + e3);
            float4 w4 = make_float4(e0 * inv, e1 * inv, e2 * inv, e3 * inv);
            *(float4*)(lds_attn + tb * ABAT + tn * NSLOT) = w4;
        }
        __syncthreads();
        // ---- C (slot rows x d-chunk): updates = attn @ v ----
        {
            const float* ab = lds_attn + sb * ABAT + ss;
            float a[NTOK];
            #pragma unroll
            for (int n = 0; n < NTOK; ++n) a[n] = ab[n * NSLOT];
            const float* vb = lds_v + sb * VBAT + dlo;
            float acc[8];
            #pragma unroll
            for (int j = 0; j < 8; ++j) acc[j] = 0.f;
            #pragma unroll
            for (int n = 0; n < NTOK; ++n) {
                const float* vr = vb + n * VROW;
                #pragma unroll
                for (int j = 0; j < 8; ++j)
                    acc[j] = fmaf(a[n], vr[j], acc[j]);
            }
            float* ud = lds_upd + sb * SBAT + ss * SROW + dlo;
            #pragma unroll
            for (int j = 0; j < 8; ++j) ud[j] = acc[j];
        }
        __syncthreads();
        // ---- D (slot rows x d-chunk): GRUCell ----
        {
            float u[DD], h[DD];
            const float* ur = lds_upd   + sb * SBAT + ss * SROW;
            const float* hr = lds_slots + sb * SBAT + ss * SROW;
            #pragma unroll
            for (int e = 0; e < DD; ++e) { u[e] = ur[e]; h[e] = hr[e]; }
            __syncthreads();   // all lds_slots reads done before any write
            float* sdst = lds_slots + sb * SBAT + ss * SROW;
            float* odst = out + ((size_t)(blockBase + sb) * NSLOT + ss) * DD;
            #pragma unroll 2
            for (int j = 0; j < 8; ++j) {
                int d = dlo + j;
                float gir = gbih[d], giz = gbih[DD + d], gin = gbih[2 * DD + d];
                float ghr = gbhh[d], ghz = gbhh[DD + d], ghn = gbhh[2 * DD + d];
                #pragma unroll
                for (int e = 0; e < DD; ++e) {
                    float ue = u[e], he = h[e];
                    gir = fmaf(ue, gwih[d * DD + e],            gir);
                    giz = fmaf(ue, gwih[(DD + d) * DD + e],     giz);
                    gin = fmaf(ue, gwih[(2 * DD + d) * DD + e], gin);
                    ghr = fmaf(he, gwhh[d * DD + e],            ghr);
                    ghz = fmaf(he, gwhh[(DD + d) * DD + e],     ghz);
                    ghn = fmaf(he, gwhh[(2 * DD + d) * DD + e], ghn);
                }
                float r  = sigm(gir + ghr);
                float z  = sigm(giz + ghz);
                float nn = tanhf_(gin + r * ghn);
                float hn = (1.0f - z) * nn + z * h[d];
                if (it < 2) sdst[d] = hn;
                else        odst[d] = hn;
            }
        }
        __syncthreads();
    }
}

extern "C" void kernel_launch(void* const* d_in, const int* in_sizes, int n_in,
                              void* d_out, int out_size, void* d_ws, size_t ws_size,
                              hipStream_t stream) {
    const float* latent  = (const float*)d_in[0];
    const float* slot_mu = (const float*)d_in[1];
    const float* w_in    = (const float*)d_in[2];
    const float* b_in    = (const float*)d_in[3];
    const float* ln_g    = (const float*)d_in[4];
    const float* ln_b    = (const float*)d_in[5];
    const float* wq      = (const float*)d_in[6];
    const float* wk      = (const float*)d_in[7];
    const float* wv      = (const float*)d_in[8];
    const float* gwih    = (const float*)d_in[9];
    const float* gwhh    = (const float*)d_in[10];
    const float* gbih    = (const float*)d_in[11];
    const float* gbhh    = (const float*)d_in[12];
    float* out = (float*)d_out;

    const int B = in_sizes[0] / (CIN * NTOK);   // 65536
    const int grid = B / GB;                    // 4096
    slotattn_kernel<<<grid, 256, 0, stream>>>(latent, slot_mu, w_in, b_in, ln_g, ln_b,
                                              wq, wk, wv, gwih, gwhh, gbih, gbhh, out);
}

// Round 3
// 254.262 us; speedup vs baseline: 4.2342x; 4.2342x over previous
//
#include <hip/hip_runtime.h>

typedef short bf16x8 __attribute__((ext_vector_type(8)));
typedef float f32x4  __attribute__((ext_vector_type(4)));
typedef unsigned int u32x4 __attribute__((ext_vector_type(4)));

#define MFMA16(a,b,c) __builtin_amdgcn_mfma_f32_16x16x32_bf16(a,b,c,0,0,0)
#define SCALE_F 0.17677669529663687f

union FragU { u32x4 u4; unsigned int u[4]; bf16x8 f; };

__device__ __forceinline__ unsigned short rne1(float x){
  unsigned int u = __float_as_uint(x);
  return (unsigned short)((u + 0x7fffu + ((u>>16)&1u)) >> 16);
}
__device__ __forceinline__ unsigned int tr2(float a, float b){
  return (__float_as_uint(a)>>16) | (__float_as_uint(b)&0xffff0000u);
}
// trunc-based pair split (for paired values)
__device__ __forceinline__ void split2(float a, float b, unsigned int& h, unsigned int& l){
  float ha = __uint_as_float(__float_as_uint(a)&0xffff0000u);
  float hb = __uint_as_float(__float_as_uint(b)&0xffff0000u);
  h = tr2(a,b);
  l = tr2(a-ha, b-hb);
}
// rne-based scalar split
__device__ __forceinline__ void split1(float x, unsigned short& h, unsigned short& l){
  h = rne1(x);
  float hf = __uint_as_float((unsigned)h<<16);
  l = rne1(x - hf);
}
__device__ __forceinline__ float join1(unsigned short h, unsigned short l){
  return __uint_as_float((unsigned)h<<16) + __uint_as_float((unsigned)l<<16);
}

struct WPair { bf16x8 h, l; };

// hi/lo B-fragments for one 16-col tile of a row-major [rows][32] fp32 weight.
// lane: col = m (+16*til), k-dim e = 8*g + j  ->  w[(16*til+m)*32 + 8*g + j]
__device__ __forceinline__ WPair load_wfrag2(const float* __restrict__ w,
                                             int til, int m, int g, float scale){
  const float* p = w + (size_t)(til*16 + m)*32 + g*8;
  f32x4 a = *(const f32x4*)p;
  f32x4 b = *(const f32x4*)(p+4);
  float v[8] = {a[0]*scale,a[1]*scale,a[2]*scale,a[3]*scale,
                b[0]*scale,b[1]*scale,b[2]*scale,b[3]*scale};
  FragU hh, ll;
  #pragma unroll
  for (int i=0;i<4;++i){
    unsigned short h0, l0, h1, l1;
    split1(v[2*i],   h0, l0);
    split1(v[2*i+1], h1, l1);
    hh.u[i] = (unsigned)h0 | ((unsigned)h1<<16);
    ll.u[i] = (unsigned)l0 | ((unsigned)l1<<16);
  }
  WPair r; r.h = hh.f; r.l = ll.f; return r;
}

// 3-term double-bf16 product: (Ah+Al)(Bh+Bl) ~= AhBh + AlBh + AhBl
__device__ __forceinline__ f32x4 mfma3(bf16x8 ah, bf16x8 al, bf16x8 bh, bf16x8 bl, f32x4 c){
  c = MFMA16(ah, bh, c);
  c = MFMA16(al, bh, c);
  c = MFMA16(ah, bl, c);
  return c;
}

// Per-wave LDS (26624 B), 2 waves/block = 53248 B:
//   +0      kb_hi  bf16 [4][16][32]  (4096)
//   +4096   kb_lo  bf16 [4][16][32]  (4096)
//   +8192   vt_hi  bf16 [4][32][16]  (4096)
//   +12288  vt_lo  bf16 [4][32][16]  (4096)
//   +16384  U (10240):
//     phase A/C: x_hi [4][16][40] bf16 (5120) | x_lo (5120)
//     iters: s_hi/s_lo/q_hi/q_lo/u_hi/u_lo [16][32] bf16 (1024 ea) | attn f32 [4][4][20] (1280)
__global__ __launch_bounds__(128, 2)
void slotattn_mfma(const float* __restrict__ latent,
                   const float* __restrict__ slot_mu,
                   const float* __restrict__ w_in,
                   const float* __restrict__ b_in,
                   const float* __restrict__ ln_g,
                   const float* __restrict__ ln_b,
                   const float* __restrict__ wq,
                   const float* __restrict__ wk,
                   const float* __restrict__ wv,
                   const float* __restrict__ gwih,
                   const float* __restrict__ gwhh,
                   const float* __restrict__ gbih,
                   const float* __restrict__ gbhh,
                   float* __restrict__ out)
{
  __shared__ __attribute__((aligned(16))) char smem[53248];
  const int tid = threadIdx.x;
  const int w   = __builtin_amdgcn_readfirstlane(tid >> 6);  // wave 0..1
  const int l   = tid & 63;
  const int g   = l >> 4;     // local batch (token phases) / k-group (frags)
  const int m   = l & 15;     // token / column
  const int batch0 = blockIdx.x * 8 + w * 4;

  char* sw = smem + w * 26624;
  unsigned short* kbh = (unsigned short*)sw;             // [4][16][32]
  unsigned short* kbl = (unsigned short*)(sw + 4096);
  unsigned short* vth = (unsigned short*)(sw + 8192);    // [4][32][16]
  unsigned short* vtl = (unsigned short*)(sw + 12288);
  char* U = sw + 16384;
  char* xhiB = U;                                        // [4][16][40] bf16
  char* xloB = U + 5120;
  unsigned short* shi = (unsigned short*)U;              // [16][32]
  unsigned short* slo = (unsigned short*)(U + 1024);
  unsigned short* qhi = (unsigned short*)(U + 2048);
  unsigned short* qlo = (unsigned short*)(U + 3072);
  unsigned short* uhi = (unsigned short*)(U + 4096);
  unsigned short* ulo = (unsigned short*)(U + 5120);
  float* attnf = (float*)(U + 6144);                     // [4][4][20] f32

  // ---- Phase A: latent -> proj -> LN -> x hi/lo to LDS (thread = batch g, token m) ----
  {
    const float* latp = latent + (size_t)(batch0 + g) * 128 + m;
    float c[8];
    #pragma unroll
    for (int cc=0; cc<8; ++cc) c[cc] = latp[cc*16];
    float xr[32];
    #pragma unroll
    for (int d=0; d<32; ++d){
      float acc = b_in[d];
      #pragma unroll
      for (int cc=0; cc<8; ++cc) acc = fmaf(c[cc], w_in[d*8+cc], acc);
      xr[d] = acc;
    }
    float mu = 0.f;
    #pragma unroll
    for (int d=0; d<32; ++d) mu += xr[d];
    mu *= 0.03125f;
    float var = 0.f;
    #pragma unroll
    for (int d=0; d<32; ++d){ float t = xr[d]-mu; var = fmaf(t,t,var); }
    var *= 0.03125f;
    float rs = rsqrtf(var + 1e-5f);
    #pragma unroll
    for (int d=0; d<32; ++d) xr[d] = (xr[d]-mu)*rs*ln_g[d] + ln_b[d];

    unsigned int hw[16], lw[16];
    #pragma unroll
    for (int p=0; p<16; ++p) split2(xr[2*p], xr[2*p+1], hw[p], lw[p]);
    char* dsth = xhiB + g*1280 + m*80;
    char* dstl = xloB + g*1280 + m*80;
    #pragma unroll
    for (int q=0; q<4; ++q){
      u32x4 hv = { hw[4*q], hw[4*q+1], hw[4*q+2], hw[4*q+3] };
      u32x4 lv = { lw[4*q], lw[4*q+1], lw[4*q+2], lw[4*q+3] };
      *(u32x4*)(dsth + q*16) = hv;
      *(u32x4*)(dstl + q*16) = lv;
    }
  }
  asm volatile("" ::: "memory");

  // ---- Phase C: k = x@wk^T, v = x@wv^T; k hi/lo -> LDS, v^T hi/lo -> LDS ----
  {
    WPair wk0 = load_wfrag2(wk, 0, m, g, 1.f);
    WPair wk1 = load_wfrag2(wk, 1, m, g, 1.f);
    WPair wv0 = load_wfrag2(wv, 0, m, g, 1.f);
    WPair wv1 = load_wfrag2(wv, 1, m, g, 1.f);
    #pragma unroll
    for (int bt=0; bt<4; ++bt){
      FragU xh, xl;
      xh.u4 = *(const u32x4*)(xhiB + bt*1280 + m*80 + g*16);
      xl.u4 = *(const u32x4*)(xloB + bt*1280 + m*80 + g*16);
      f32x4 k0={0,0,0,0}, k1={0,0,0,0}, v0={0,0,0,0}, v1={0,0,0,0};
      k0 = mfma3(xh.f, xl.f, wk0.h, wk0.l, k0);
      k1 = mfma3(xh.f, xl.f, wk1.h, wk1.l, k1);
      v0 = mfma3(xh.f, xl.f, wv0.h, wv0.l, v0);
      v1 = mfma3(xh.f, xl.f, wv1.h, wv1.l, v1);
      unsigned short vh0[4], vl0[4], vh1[4], vl1[4];
      #pragma unroll
      for (int r=0; r<4; ++r){
        int tok = 4*g + r;                 // D row
        unsigned short h0,l0,h1,l1;
        split1(k0[r], h0, l0);
        split1(k1[r], h1, l1);
        kbh[bt*512 + tok*32 + m]      = h0;
        kbl[bt*512 + tok*32 + m]      = l0;
        kbh[bt*512 + tok*32 + m + 16] = h1;
        kbl[bt*512 + tok*32 + m + 16] = l1;
        split1(v0[r], vh0[r], vl0[r]);
        split1(v1[r], vh1[r], vl1[r]);
      }
      uint2 ph0 = { (unsigned)vh0[0] | ((unsigned)vh0[1]<<16), (unsigned)vh0[2] | ((unsigned)vh0[3]<<16) };
      uint2 pl0 = { (unsigned)vl0[0] | ((unsigned)vl0[1]<<16), (unsigned)vl0[2] | ((unsigned)vl0[3]<<16) };
      uint2 ph1 = { (unsigned)vh1[0] | ((unsigned)vh1[1]<<16), (unsigned)vh1[2] | ((unsigned)vh1[3]<<16) };
      uint2 pl1 = { (unsigned)vl1[0] | ((unsigned)vl1[1]<<16), (unsigned)vl1[2] | ((unsigned)vl1[3]<<16) };
      *(uint2*)(vth + bt*512 + m*16      + 4*g) = ph0;
      *(uint2*)(vtl + bt*512 + m*16      + 4*g) = pl0;
      *(uint2*)(vth + bt*512 + (m+16)*16 + 4*g) = ph1;
      *(uint2*)(vtl + bt*512 + (m+16)*16 + 4*g) = pl1;
    }
  }
  asm volatile("" ::: "memory");

  // ---- slots init (overwrites x region) ----
  #pragma unroll
  for (int j=0; j<8; ++j){
    int i = l + 64*j;                  // 0..511
    int row = i >> 5, d = i & 31;
    float v = slot_mu[i & 127];
    unsigned short h, lo2;
    split1(v, h, lo2);
    shi[row*32 + d] = h;
    slo[row*32 + d] = lo2;
  }

  // ---- persistent weight fragments ----
  WPair wqf0 = load_wfrag2(wq, 0, m, g, SCALE_F);
  WPair wqf1 = load_wfrag2(wq, 1, m, g, SCALE_F);
  WPair wihf[6], whhf[6];
  float bihl[6], bhhl[6];
  #pragma unroll
  for (int t=0; t<6; ++t){
    wihf[t] = load_wfrag2(gwih, t, m, g, 1.f);
    whhf[t] = load_wfrag2(gwhh, t, m, g, 1.f);
    bihl[t] = gbih[t*16 + m];
    bhhl[t] = gbhh[t*16 + m];
  }

  for (int it=0; it<3; ++it){
    asm volatile("" ::: "memory");
    // slots A fragments (16 merged batch-slot rows)
    FragU sh, sl;
    sh.u4 = *(const u32x4*)((char*)shi + m*64 + g*16);
    sl.u4 = *(const u32x4*)((char*)slo + m*64 + g*16);

    // q = slots @ (scale*wq)^T -> hi/lo to LDS
    f32x4 q0={0,0,0,0}, q1={0,0,0,0};
    q0 = mfma3(sh.f, sl.f, wqf0.h, wqf0.l, q0);
    q1 = mfma3(sh.f, sl.f, wqf1.h, wqf1.l, q1);
    #pragma unroll
    for (int r=0; r<4; ++r){
      int row = 4*g + r;
      unsigned short h0,l0,h1,l1;
      split1(q0[r], h0, l0);
      split1(q1[r], h1, l1);
      qhi[row*32 + m]      = h0;
      qlo[row*32 + m]      = l0;
      qhi[row*32 + m + 16] = h1;
      qlo[row*32 + m + 16] = l1;
    }
    asm volatile("" ::: "memory");

    // logits per batch: D = q_b . k_b^T
    f32x4 la[4];
    #pragma unroll
    for (int bt=0; bt<4; ++bt){
      FragU qah, qal, kfh, kfl;
      int arow = 4*bt + (m & 3);
      qah.u4 = *(const u32x4*)((char*)qhi + arow*64 + g*16);
      qal.u4 = *(const u32x4*)((char*)qlo + arow*64 + g*16);
      kfh.u4 = *(const u32x4*)((char*)kbh + bt*1024 + m*64 + g*16);
      kfl.u4 = *(const u32x4*)((char*)kbl + bt*1024 + m*64 + g*16);
      f32x4 acc={0,0,0,0};
      la[bt] = mfma3(qah.f, qal.f, kfh.f, kfl.f, acc);
    }
    // softmax over slots (lanes 0..15: slot = reg, token = lane)
    if (l < 16){
      #pragma unroll
      for (int bt=0; bt<4; ++bt){
        float l0=la[bt][0], l1=la[bt][1], l2=la[bt][2], l3=la[bt][3];
        float mx = fmaxf(fmaxf(l0,l1), fmaxf(l2,l3));
        float e0=__expf(l0-mx), e1=__expf(l1-mx), e2=__expf(l2-mx), e3=__expf(l3-mx);
        float inv = 1.f/(e0+e1+e2+e3);
        attnf[bt*80 + 0*20 + l] = e0*inv;
        attnf[bt*80 + 1*20 + l] = e1*inv;
        attnf[bt*80 + 2*20 + l] = e2*inv;
        attnf[bt*80 + 3*20 + l] = e3*inv;
      }
    }
    asm volatile("" ::: "memory");

    // updates = attn @ v   (K = 32 tokens, upper 16 zeroed via A rows)
    #pragma unroll
    for (int bt=0; bt<4; ++bt){
      const float* ap = attnf + bt*80 + (m & 3)*20 + (g & 1)*8;
      f32x4 a0 = *(const f32x4*)ap;
      f32x4 a1 = *(const f32x4*)(ap + 4);
      FragU afh, afl;
      split2(a0[0],a0[1], afh.u[0], afl.u[0]);
      split2(a0[2],a0[3], afh.u[1], afl.u[1]);
      split2(a1[0],a1[1], afh.u[2], afl.u[2]);
      split2(a1[2],a1[3], afh.u[3], afl.u[3]);
      if (g >= 2){
        afh.u[0]=0; afh.u[1]=0; afh.u[2]=0; afh.u[3]=0;
        afl.u[0]=0; afl.u[1]=0; afl.u[2]=0; afl.u[3]=0;
      }
      FragU vbh0, vbl0, vbh1, vbl1;
      vbh0.u4 = *(const u32x4*)((char*)vth + bt*1024 + m*32 + (g&1)*16);
      vbl0.u4 = *(const u32x4*)((char*)vtl + bt*1024 + m*32 + (g&1)*16);
      vbh1.u4 = *(const u32x4*)((char*)vth + bt*1024 + (m+16)*32 + (g&1)*16);
      vbl1.u4 = *(const u32x4*)((char*)vtl + bt*1024 + (m+16)*32 + (g&1)*16);
      f32x4 u0={0,0,0,0}, u1={0,0,0,0};
      u0 = mfma3(afh.f, afl.f, vbh0.f, vbl0.f, u0);
      u1 = mfma3(afh.f, afl.f, vbh1.f, vbl1.f, u1);
      if (l < 16){
        #pragma unroll
        for (int r=0; r<4; ++r){
          int row = 4*bt + r;
          unsigned short h0,l0,h1,l1;
          split1(u0[r], h0, l0);
          split1(u1[r], h1, l1);
          uhi[row*32 + m]      = h0;
          ulo[row*32 + m]      = l0;
          uhi[row*32 + m + 16] = h1;
          ulo[row*32 + m + 16] = l1;
        }
      }
    }
    asm volatile("" ::: "memory");

    // GRU: gi = upd@wih^T + bih ; gh = h@whh^T + bhh  (16 rows, N=96 = 6 tiles)
    FragU uh, ul;
    uh.u4 = *(const u32x4*)((char*)uhi + m*64 + g*16);
    ul.u4 = *(const u32x4*)((char*)ulo + m*64 + g*16);
    f32x4 gi[6], gh[6];
    #pragma unroll
    for (int t=0; t<6; ++t){
      f32x4 ci = { bihl[t], bihl[t], bihl[t], bihl[t] };
      gi[t] = mfma3(uh.f, ul.f, wihf[t].h, wihf[t].l, ci);
      f32x4 ch = { bhhl[t], bhhl[t], bhhl[t], bhhl[t] };
      gh[t] = mfma3(sh.f, sl.f, whhf[t].h, whhf[t].l, ch);
    }
    bool last = (it == 2);
    #pragma unroll
    for (int T=0; T<2; ++T){
      #pragma unroll
      for (int r=0; r<4; ++r){
        float ir = gi[T][r],   iz = gi[2+T][r], inn = gi[4+T][r];
        float hr = gh[T][r],   hz = gh[2+T][r], hn  = gh[4+T][r];
        float rr = 1.f/(1.f + __expf(-(ir+hr)));
        float zz = 1.f/(1.f + __expf(-(iz+hz)));
        float pre = inn + rr*hn;
        float nn = 1.f - 2.f/(__expf(2.f*pre) + 1.f);
        int row = 4*g + r, d = m + 16*T;
        float hval = join1(shi[row*32 + d], slo[row*32 + d]);
        float hnew = nn + zz*(hval - nn);
        if (last){
          out[(size_t)(batch0+g)*128 + r*32 + d] = hnew;
        } else {
          unsigned short h2, l2;
          split1(hnew, h2, l2);
          shi[row*32 + d] = h2;
          slo[row*32 + d] = l2;
        }
      }
    }
  }
}

extern "C" void kernel_launch(void* const* d_in, const int* in_sizes, int n_in,
                              void* d_out, int out_size, void* d_ws, size_t ws_size,
                              hipStream_t stream) {
  const float* latent  = (const float*)d_in[0];
  const float* slot_mu = (const float*)d_in[1];
  const float* w_in    = (const float*)d_in[2];
  const float* b_in    = (const float*)d_in[3];
  const float* ln_g    = (const float*)d_in[4];
  const float* ln_b    = (const float*)d_in[5];
  const float* wq      = (const float*)d_in[6];
  const float* wk      = (const float*)d_in[7];
  const float* wv      = (const float*)d_in[8];
  const float* gwih    = (const float*)d_in[9];
  const float* gwhh    = (const float*)d_in[10];
  const float* gbih    = (const float*)d_in[11];
  const float* gbhh    = (const float*)d_in[12];
  float* out = (float*)d_out;

  const int B = in_sizes[0] >> 7;    // 65536
  const int grid = B >> 3;           // 8192 blocks of 128 threads (2 waves, 8 batches)
  slotattn_mfma<<<grid, 128, 0, stream>>>(latent, slot_mu, w_in, b_in, ln_g, ln_b,
                                          wq, wk, wv, gwih, gwhh, gbih, gbhh, out);
}

// Round 4
// 222.676 us; speedup vs baseline: 4.8349x; 1.1418x over previous
//
#include <hip/hip_runtime.h>

typedef short bf16x8 __attribute__((ext_vector_type(8)));
typedef float f32x4  __attribute__((ext_vector_type(4)));
typedef unsigned int u32x4 __attribute__((ext_vector_type(4)));

#define MFMA16(a,b,c) __builtin_amdgcn_mfma_f32_16x16x32_bf16(a,b,c,0,0,0)
#define SCALE_F 0.17677669529663687f

union FragU { u32x4 u4; unsigned int u[4]; bf16x8 f; };
struct WPair { bf16x8 h, l; };

__device__ __forceinline__ unsigned short rne1(float x){
  unsigned int u = __float_as_uint(x);
  return (unsigned short)((u + 0x7fffu + ((u>>16)&1u)) >> 16);
}
__device__ __forceinline__ void split1(float x, unsigned short& h, unsigned short& l){
  h = rne1(x);
  float hf = __uint_as_float((unsigned)h<<16);
  l = rne1(x - hf);
}
__device__ __forceinline__ void trsplit(float x, unsigned short& h, unsigned short& l){
  unsigned int u = __float_as_uint(x);
  h = (unsigned short)(u>>16);
  l = rne1(x - __uint_as_float(u & 0xffff0000u));
}
__device__ __forceinline__ unsigned int tr2(float a, float b){
  return (__float_as_uint(a)>>16) | (__float_as_uint(b)&0xffff0000u);
}
__device__ __forceinline__ void split2(float a, float b, unsigned int& h, unsigned int& l){
  float ha = __uint_as_float(__float_as_uint(a)&0xffff0000u);
  float hb = __uint_as_float(__float_as_uint(b)&0xffff0000u);
  h = tr2(a,b);
  l = tr2(a-ha, b-hb);
}
__device__ __forceinline__ float join1(unsigned short h, unsigned short l){
  return __uint_as_float((unsigned)h<<16) + __uint_as_float((unsigned)l<<16);
}
__device__ __forceinline__ f32x4 mfma3(bf16x8 ah, bf16x8 al, bf16x8 bh, bf16x8 bl, f32x4 c){
  c = MFMA16(ah, bh, c);
  c = MFMA16(al, bh, c);
  c = MFMA16(ah, bl, c);
  return c;
}

// ---- ws layout (u32 units): frag(t,l) at (t*64+l)*8 : 4 u32 hi, 4 u32 lo.
// tiles: 0-1 wfuseT, 2-3 wv, 4-9 gwih, 10-15 gwhh.  byte 32768: slot_mu hi u16[128], lo u16[128].
__device__ __forceinline__ void store_frag(unsigned int* ws, int t, int l, const float* v){
  FragU hh, ll;
  #pragma unroll
  for (int i=0;i<4;++i){
    unsigned short h0,l0,h1,l1;
    split1(v[2*i],   h0, l0);
    split1(v[2*i+1], h1, l1);
    hh.u[i] = (unsigned)h0 | ((unsigned)h1<<16);
    ll.u[i] = (unsigned)l0 | ((unsigned)l1<<16);
  }
  *(u32x4*)(ws + (size_t)(t*64+l)*8)     = hh.u4;
  *(u32x4*)(ws + (size_t)(t*64+l)*8 + 4) = ll.u4;
}
__device__ __forceinline__ WPair load_pre(const unsigned int* ws, int t, int l){
  const unsigned int* p = ws + (size_t)(t*64+l)*8;
  FragU a,b; a.u4 = *(const u32x4*)p; b.u4 = *(const u32x4*)(p+4);
  WPair r; r.h = a.f; r.l = b.f; return r;
}

__global__ void prep_kernel(const float* __restrict__ slot_mu,
                            const float* __restrict__ wq,
                            const float* __restrict__ wk,
                            const float* __restrict__ wv,
                            const float* __restrict__ gwih,
                            const float* __restrict__ gwhh,
                            unsigned int* __restrict__ ws)
{
  const int l = threadIdx.x & 63;
  const int g = l >> 4, m = l & 15;
  float v[8];
  // wfuseT[d][c] = SCALE * sum_dp wq[dp][d]*wk[dp][c]; frag val = wfuseT[t*16+m][8g+j]
  #pragma unroll
  for (int t=0; t<2; ++t){
    #pragma unroll
    for (int j=0;j<8;++j){
      int d = t*16+m, c = 8*g+j;
      float acc = 0.f;
      for (int dp=0; dp<32; ++dp) acc = fmaf(wq[dp*32+d], wk[dp*32+c], acc);
      v[j] = acc * SCALE_F;
    }
    store_frag(ws, t, l, v);
  }
  // plain [out][32] weights: frag val = w[(tt*16+m)*32 + 8g+j]
  #pragma unroll
  for (int tt=0; tt<2; ++tt){
    #pragma unroll
    for (int j=0;j<8;++j) v[j] = wv[(tt*16+m)*32 + 8*g + j];
    store_frag(ws, 2+tt, l, v);
  }
  for (int tt=0; tt<6; ++tt){
    #pragma unroll
    for (int j=0;j<8;++j) v[j] = gwih[(tt*16+m)*32 + 8*g + j];
    store_frag(ws, 4+tt, l, v);
  }
  for (int tt=0; tt<6; ++tt){
    #pragma unroll
    for (int j=0;j<8;++j) v[j] = gwhh[(tt*16+m)*32 + 8*g + j];
    store_frag(ws, 10+tt, l, v);
  }
  // slot_mu pre-split
  unsigned short* s16 = (unsigned short*)(ws + 8192);
  #pragma unroll
  for (int p=0;p<2;++p){
    int idx = 2*l + p;
    unsigned short h, lo;
    split1(slot_mu[idx], h, lo);
    s16[idx] = h; s16[128+idx] = lo;
  }
}

// Per-wave LDS region (24832 B), 2 waves/block = 49664 B.
#define KQH 0       // [4][16][40] u16 : bt*1280 + tok*80 + d*2
#define KQL 5120
#define VTH 10240   // [4][32][16] u16 : bt*1024 + drow*32 + tok*2
#define VTL 14336
#define SHI 18432   // [16][40] u16 : row*80 + d*2
#define SLO 19712
#define UHI 20992
#define ULO 22272
#define ATT 23552   // [4][4][20] f32
#define XH  0       // [4][16][40] u16 (aliases KQ region; dead after phase C reads)
#define XL  5120

__global__ __launch_bounds__(128, 2)
void slotattn_mfma(const float* __restrict__ latent,
                   const float* __restrict__ w_in,
                   const float* __restrict__ b_in,
                   const float* __restrict__ ln_g,
                   const float* __restrict__ ln_b,
                   const float* __restrict__ gbih,
                   const float* __restrict__ gbhh,
                   const unsigned int* __restrict__ ws,
                   float* __restrict__ out)
{
  __shared__ __attribute__((aligned(16))) char smem[49664];
  const int tid = threadIdx.x;
  const int w   = __builtin_amdgcn_readfirstlane(tid >> 6);
  const int l   = tid & 63;
  const int g   = l >> 4;
  const int m   = l & 15;
  const int batch0 = blockIdx.x * 8 + w * 4;
  char* sw = smem + w * 24832;

  // ---- Phase A: latent -> proj -> LN -> x hi/lo to LDS (thread = batch g, token m) ----
  {
    const float* latp = latent + (size_t)(batch0 + g) * 128 + m;
    float c[8];
    #pragma unroll
    for (int cc=0; cc<8; ++cc) c[cc] = latp[cc*16];
    float xr[32];
    #pragma unroll
    for (int d=0; d<32; ++d){
      float acc = b_in[d];
      #pragma unroll
      for (int cc=0; cc<8; ++cc) acc = fmaf(c[cc], w_in[d*8+cc], acc);
      xr[d] = acc;
    }
    float mu = 0.f;
    #pragma unroll
    for (int d=0; d<32; ++d) mu += xr[d];
    mu *= 0.03125f;
    float var = 0.f;
    #pragma unroll
    for (int d=0; d<32; ++d){ float t = xr[d]-mu; var = fmaf(t,t,var); }
    var *= 0.03125f;
    float rs = rsqrtf(var + 1e-5f);
    #pragma unroll
    for (int d=0; d<32; ++d) xr[d] = (xr[d]-mu)*rs*ln_g[d] + ln_b[d];

    unsigned int hw[16], lw[16];
    #pragma unroll
    for (int p=0; p<16; ++p) split2(xr[2*p], xr[2*p+1], hw[p], lw[p]);
    char* dsth = sw + XH + g*1280 + m*80;
    char* dstl = sw + XL + g*1280 + m*80;
    #pragma unroll
    for (int q=0; q<4; ++q){
      u32x4 hv = { hw[4*q], hw[4*q+1], hw[4*q+2], hw[4*q+3] };
      u32x4 lv = { lw[4*q], lw[4*q+1], lw[4*q+2], lw[4*q+3] };
      *(u32x4*)(dsth + q*16) = hv;
      *(u32x4*)(dstl + q*16) = lv;
    }
  }
  asm volatile("" ::: "memory");

  // ---- Phase C: kq = x@wfuse, v = x@wv^T ; kq hi/lo -> LDS, v^T hi/lo -> LDS ----
  {
    // read ALL x fragments to regs first (x aliases kq region)
    FragU xh[4], xl[4];
    #pragma unroll
    for (int bt=0; bt<4; ++bt){
      xh[bt].u4 = *(const u32x4*)(sw + XH + bt*1280 + m*80 + g*16);
      xl[bt].u4 = *(const u32x4*)(sw + XL + bt*1280 + m*80 + g*16);
    }
    asm volatile("" ::: "memory");
    WPair wf0 = load_pre(ws, 0, l), wf1 = load_pre(ws, 1, l);
    WPair wv0 = load_pre(ws, 2, l), wv1 = load_pre(ws, 3, l);
    #pragma unroll
    for (int bt=0; bt<4; ++bt){
      f32x4 z = {0,0,0,0};
      f32x4 k0 = mfma3(xh[bt].f, xl[bt].f, wf0.h, wf0.l, z);
      f32x4 k1 = mfma3(xh[bt].f, xl[bt].f, wf1.h, wf1.l, z);
      f32x4 v0 = mfma3(xh[bt].f, xl[bt].f, wv0.h, wv0.l, z);
      f32x4 v1 = mfma3(xh[bt].f, xl[bt].f, wv1.h, wv1.l, z);
      unsigned short vh0[4], vl0[4], vh1[4], vl1[4];
      #pragma unroll
      for (int r=0; r<4; ++r){
        int tok = 4*g + r;
        unsigned short h0,l0,h1,l1;
        trsplit(k0[r], h0, l0);
        trsplit(k1[r], h1, l1);
        *(unsigned short*)(sw + KQH + bt*1280 + tok*80 + 2*m)      = h0;
        *(unsigned short*)(sw + KQL + bt*1280 + tok*80 + 2*m)      = l0;
        *(unsigned short*)(sw + KQH + bt*1280 + tok*80 + 2*(m+16)) = h1;
        *(unsigned short*)(sw + KQL + bt*1280 + tok*80 + 2*(m+16)) = l1;
        trsplit(v0[r], vh0[r], vl0[r]);
        trsplit(v1[r], vh1[r], vl1[r]);
      }
      uint2 ph0 = { (unsigned)vh0[0] | ((unsigned)vh0[1]<<16), (unsigned)vh0[2] | ((unsigned)vh0[3]<<16) };
      uint2 pl0 = { (unsigned)vl0[0] | ((unsigned)vl0[1]<<16), (unsigned)vl0[2] | ((unsigned)vl0[3]<<16) };
      uint2 ph1 = { (unsigned)vh1[0] | ((unsigned)vh1[1]<<16), (unsigned)vh1[2] | ((unsigned)vh1[3]<<16) };
      uint2 pl1 = { (unsigned)vl1[0] | ((unsigned)vl1[1]<<16), (unsigned)vl1[2] | ((unsigned)vl1[3]<<16) };
      *(uint2*)(sw + VTH + bt*1024 + m*32      + 8*g) = ph0;
      *(uint2*)(sw + VTL + bt*1024 + m*32      + 8*g) = pl0;
      *(uint2*)(sw + VTH + bt*1024 + (m+16)*32 + 8*g) = ph1;
      *(uint2*)(sw + VTL + bt*1024 + (m+16)*32 + 8*g) = pl1;
    }
  }

  // ---- slots init from pre-split slot_mu ----
  {
    const unsigned short* s16 = (const unsigned short*)(ws + 8192);
    #pragma unroll
    for (int j=0; j<8; ++j){
      int i = l + 64*j;
      int row = i >> 5, d = i & 31, idx = i & 127;
      *(unsigned short*)(sw + SHI + row*80 + 2*d) = s16[idx];
      *(unsigned short*)(sw + SLO + row*80 + 2*d) = s16[128+idx];
    }
  }

  // ---- persistent GRU weight fragments + biases ----
  WPair wihf[6], whhf[6];
  float bihl[6], bhhl[6];
  #pragma unroll
  for (int t=0; t<6; ++t){
    wihf[t] = load_pre(ws, 4+t, l);
    whhf[t] = load_pre(ws, 10+t, l);
    bihl[t] = gbih[t*16 + m];
    bhhl[t] = gbhh[t*16 + m];
  }

  for (int it=0; it<3; ++it){
    asm volatile("" ::: "memory");
    FragU sh, sl;
    sh.u4 = *(const u32x4*)(sw + SHI + m*80 + g*16);
    sl.u4 = *(const u32x4*)(sw + SLO + m*80 + g*16);

    // logits = slots @ kq^T per batch; keep batch g (rows replicated: row 4q+r = slot r)
    f32x4 ls = {0,0,0,0};
    #pragma unroll
    for (int bt=0; bt<4; ++bt){
      FragU ah, al, bh, bl;
      int arow = 4*bt + (m&3);
      ah.u4 = *(const u32x4*)(sw + SHI + arow*80 + g*16);
      al.u4 = *(const u32x4*)(sw + SLO + arow*80 + g*16);
      bh.u4 = *(const u32x4*)(sw + KQH + bt*1280 + m*80 + g*16);
      bl.u4 = *(const u32x4*)(sw + KQL + bt*1280 + m*80 + g*16);
      f32x4 z = {0,0,0,0};
      f32x4 la = mfma3(ah.f, al.f, bh.f, bl.f, z);
      if (bt==0) ls = la;
      else {
        bool take = (g==bt);
        #pragma unroll
        for (int c2=0;c2<4;++c2) ls[c2] = take ? la[c2] : ls[c2];
      }
    }
    // softmax over slots: all lanes, batch = g, token = m
    {
      float mx = fmaxf(fmaxf(ls[0],ls[1]), fmaxf(ls[2],ls[3]));
      float e0=__expf(ls[0]-mx), e1=__expf(ls[1]-mx), e2=__expf(ls[2]-mx), e3=__expf(ls[3]-mx);
      float inv = 1.f/(e0+e1+e2+e3);
      float* att = (float*)(sw + ATT);
      att[g*80 + 0*20 + m] = e0*inv;
      att[g*80 + 1*20 + m] = e1*inv;
      att[g*80 + 2*20 + m] = e2*inv;
      att[g*80 + 3*20 + m] = e3*inv;
    }
    asm volatile("" ::: "memory");

    // updates = attn @ v; keep batch g
    f32x4 u0s = {0,0,0,0}, u1s = {0,0,0,0};
    #pragma unroll
    for (int bt=0; bt<4; ++bt){
      const float* ap = (const float*)(sw + ATT) + bt*80 + (m&3)*20 + (g&1)*8;
      f32x4 a0 = *(const f32x4*)ap;
      f32x4 a1 = *(const f32x4*)(ap+4);
      FragU afh, afl;
      split2(a0[0],a0[1], afh.u[0], afl.u[0]);
      split2(a0[2],a0[3], afh.u[1], afl.u[1]);
      split2(a1[0],a1[1], afh.u[2], afl.u[2]);
      split2(a1[2],a1[3], afh.u[3], afl.u[3]);
      if (g >= 2){
        #pragma unroll
        for (int c2=0;c2<4;++c2){ afh.u[c2]=0; afl.u[c2]=0; }
      }
      FragU vh0,vl0,vh1,vl1;
      vh0.u4 = *(const u32x4*)(sw + VTH + bt*1024 + m*32      + (g&1)*16);
      vl0.u4 = *(const u32x4*)(sw + VTL + bt*1024 + m*32      + (g&1)*16);
      vh1.u4 = *(const u32x4*)(sw + VTH + bt*1024 + (m+16)*32 + (g&1)*16);
      vl1.u4 = *(const u32x4*)(sw + VTL + bt*1024 + (m+16)*32 + (g&1)*16);
      f32x4 z = {0,0,0,0};
      f32x4 u0 = mfma3(afh.f, afl.f, vh0.f, vl0.f, z);
      f32x4 u1 = mfma3(afh.f, afl.f, vh1.f, vl1.f, z);
      if (bt==0){ u0s = u0; u1s = u1; }
      else {
        bool take = (g==bt);
        #pragma unroll
        for (int c2=0;c2<4;++c2){ u0s[c2] = take?u0[c2]:u0s[c2]; u1s[c2] = take?u1[c2]:u1s[c2]; }
      }
    }
    // write u rows 4g+r (all lanes productive)
    #pragma unroll
    for (int r=0;r<4;++r){
      int row = 4*g + r;
      unsigned short h0,l0,h1,l1;
      trsplit(u0s[r],h0,l0); trsplit(u1s[r],h1,l1);
      *(unsigned short*)(sw + UHI + row*80 + 2*m)      = h0;
      *(unsigned short*)(sw + ULO + row*80 + 2*m)      = l0;
      *(unsigned short*)(sw + UHI + row*80 + 2*(m+16)) = h1;
      *(unsigned short*)(sw + ULO + row*80 + 2*(m+16)) = l1;
    }
    asm volatile("" ::: "memory");

    // GRU
    FragU uh, ul;
    uh.u4 = *(const u32x4*)(sw + UHI + m*80 + g*16);
    ul.u4 = *(const u32x4*)(sw + ULO + m*80 + g*16);
    f32x4 gi[6], gh[6];
    #pragma unroll
    for (int t=0;t<6;++t){
      f32x4 ci = { bihl[t], bihl[t], bihl[t], bihl[t] };
      gi[t] = mfma3(uh.f, ul.f, wihf[t].h, wihf[t].l, ci);
      f32x4 ch = { bhhl[t], bhhl[t], bhhl[t], bhhl[t] };
      gh[t] = mfma3(sh.f, sl.f, whhf[t].h, whhf[t].l, ch);
    }
    bool last = (it==2);
    #pragma unroll
    for (int T=0;T<2;++T){
      #pragma unroll
      for (int r=0;r<4;++r){
        float ir=gi[T][r], iz=gi[2+T][r], inn=gi[4+T][r];
        float hr=gh[T][r], hz=gh[2+T][r], hn=gh[4+T][r];
        float rr = 1.f/(1.f+__expf(-(ir+hr)));
        float zz = 1.f/(1.f+__expf(-(iz+hz)));
        float pre = inn + rr*hn;
        float nn = 1.f - 2.f/(__expf(2.f*pre)+1.f);
        int row = 4*g+r, d = m + 16*T;
        float hval = join1(*(const unsigned short*)(sw+SHI+row*80+2*d),
                           *(const unsigned short*)(sw+SLO+row*80+2*d));
        float hnew = nn + zz*(hval-nn);
        if (last){
          out[(size_t)(batch0+g)*128 + r*32 + d] = hnew;
        } else {
          unsigned short h2,l2;
          trsplit(hnew,h2,l2);
          *(unsigned short*)(sw+SHI+row*80+2*d) = h2;
          *(unsigned short*)(sw+SLO+row*80+2*d) = l2;
        }
      }
    }
  }
}

extern "C" void kernel_launch(void* const* d_in, const int* in_sizes, int n_in,
                              void* d_out, int out_size, void* d_ws, size_t ws_size,
                              hipStream_t stream) {
  const float* latent  = (const float*)d_in[0];
  const float* slot_mu = (const float*)d_in[1];
  const float* w_in    = (const float*)d_in[2];
  const float* b_in    = (const float*)d_in[3];
  const float* ln_g    = (const float*)d_in[4];
  const float* ln_b    = (const float*)d_in[5];
  const float* wq      = (const float*)d_in[6];
  const float* wk      = (const float*)d_in[7];
  const float* wv      = (const float*)d_in[8];
  const float* gwih    = (const float*)d_in[9];
  const float* gwhh    = (const float*)d_in[10];
  const float* gbih    = (const float*)d_in[11];
  const float* gbhh    = (const float*)d_in[12];
  float* out = (float*)d_out;
  unsigned int* ws = (unsigned int*)d_ws;

  prep_kernel<<<1, 64, 0, stream>>>(slot_mu, wq, wk, wv, gwih, gwhh, ws);

  const int B = in_sizes[0] >> 7;    // 65536
  const int grid = B >> 3;           // 8192 blocks x 128 threads (2 waves, 8 batches)
  slotattn_mfma<<<grid, 128, 0, stream>>>(latent, w_in, b_in, ln_g, ln_b,
                                          gbih, gbhh, ws, out);
}

// Round 5
// 161.944 us; speedup vs baseline: 6.6480x; 1.3750x over previous
//
#include <hip/hip_runtime.h>

typedef short bf16x8 __attribute__((ext_vector_type(8)));
typedef float f32x4  __attribute__((ext_vector_type(4)));
typedef unsigned int u32x4 __attribute__((ext_vector_type(4)));

#define MFMA16(a,b,c) __builtin_amdgcn_mfma_f32_16x16x32_bf16(a,b,c,0,0,0)
#define SCALE_F 0.17677669529663687f

union FragU { u32x4 u4; unsigned int u[4]; bf16x8 f; };
struct WPair { bf16x8 h, l; };

__device__ __forceinline__ unsigned short rne1(float x){
  unsigned int u = __float_as_uint(x);
  return (unsigned short)((u + 0x7fffu + ((u>>16)&1u)) >> 16);
}
__device__ __forceinline__ void split1(float x, unsigned short& h, unsigned short& l){
  h = rne1(x);
  float hf = __uint_as_float((unsigned)h<<16);
  l = rne1(x - hf);
}
__device__ __forceinline__ void trsplit(float x, unsigned short& h, unsigned short& l){
  unsigned int u = __float_as_uint(x);
  h = (unsigned short)(u>>16);
  l = rne1(x - __uint_as_float(u & 0xffff0000u));
}
__device__ __forceinline__ unsigned int tr2(float a, float b){
  return (__float_as_uint(a)>>16) | (__float_as_uint(b)&0xffff0000u);
}
__device__ __forceinline__ void split2(float a, float b, unsigned int& h, unsigned int& l){
  float ha = __uint_as_float(__float_as_uint(a)&0xffff0000u);
  float hb = __uint_as_float(__float_as_uint(b)&0xffff0000u);
  h = tr2(a,b);
  l = tr2(a-ha, b-hb);
}
__device__ __forceinline__ f32x4 mfma3(bf16x8 ah, bf16x8 al, bf16x8 bh, bf16x8 bl, f32x4 c){
  c = MFMA16(ah, bh, c);
  c = MFMA16(al, bh, c);
  c = MFMA16(ah, bl, c);
  return c;
}
__device__ __forceinline__ f32x4 mfma2(bf16x8 a, bf16x8 bh, bf16x8 bl, f32x4 c){
  c = MFMA16(a, bh, c);
  c = MFMA16(a, bl, c);
  return c;
}
__device__ __forceinline__ bf16x8 ldfrag(const char* p){
  FragU f;
  *(uint2*)&f.u[0] = *(const uint2*)p;
  *(uint2*)&f.u[2] = *(const uint2*)(p+8);
  return f.f;
}

// ws: frag(t,l) at (t*64+l)*8 u32: 4 hi, 4 lo. tiles 0-1 wfuseT, 2-3 wv, 4-9 gwih, 10-15 gwhh.
__device__ __forceinline__ void store_frag(unsigned int* ws, int t, int l, const float* v){
  FragU hh, ll;
  #pragma unroll
  for (int i=0;i<4;++i){
    unsigned short h0,l0,h1,l1;
    split1(v[2*i],   h0, l0);
    split1(v[2*i+1], h1, l1);
    hh.u[i] = (unsigned)h0 | ((unsigned)h1<<16);
    ll.u[i] = (unsigned)l0 | ((unsigned)l1<<16);
  }
  *(u32x4*)(ws + (size_t)(t*64+l)*8)     = hh.u4;
  *(u32x4*)(ws + (size_t)(t*64+l)*8 + 4) = ll.u4;
}
__device__ __forceinline__ WPair load_pre(const unsigned int* ws, int t, int l){
  const unsigned int* p = ws + (size_t)(t*64+l)*8;
  FragU a,b; a.u4 = *(const u32x4*)p; b.u4 = *(const u32x4*)(p+4);
  WPair r; r.h = a.f; r.l = b.f; return r;
}

__global__ void prep_kernel(const float* __restrict__ wq,
                            const float* __restrict__ wk,
                            const float* __restrict__ wv,
                            const float* __restrict__ gwih,
                            const float* __restrict__ gwhh,
                            unsigned int* __restrict__ ws)
{
  const int l = threadIdx.x & 63;
  const int g = l >> 4, m = l & 15;
  float v[8];
  // wfuseT[d][c] = SCALE * sum_dp wq[dp][d]*wk[dp][c]
  #pragma unroll
  for (int t=0; t<2; ++t){
    #pragma unroll
    for (int j=0;j<8;++j){
      int d = t*16+m, c = 8*g+j;
      float acc = 0.f;
      for (int dp=0; dp<32; ++dp) acc = fmaf(wq[dp*32+d], wk[dp*32+c], acc);
      v[j] = acc * SCALE_F;
    }
    store_frag(ws, t, l, v);
  }
  #pragma unroll
  for (int tt=0; tt<2; ++tt){
    #pragma unroll
    for (int j=0;j<8;++j) v[j] = wv[(tt*16+m)*32 + 8*g + j];
    store_frag(ws, 2+tt, l, v);
  }
  for (int tt=0; tt<6; ++tt){
    #pragma unroll
    for (int j=0;j<8;++j) v[j] = gwih[(tt*16+m)*32 + 8*g + j];
    store_frag(ws, 4+tt, l, v);
  }
  for (int tt=0; tt<6; ++tt){
    #pragma unroll
    for (int j=0;j<8;++j) v[j] = gwhh[(tt*16+m)*32 + 8*g + j];
    store_frag(ws, 10+tt, l, v);
  }
}

// LDS layout (22688 B/block, 1 wave/block):
#define KQH 0       // [4][16][36]u16 : bt*1152 + n*72 + 2d   (aliased by x in phase A)
#define KQL 4608
#define VTH 9216    // [32][68]u16 : d*136 + 2*(b*16+n)
#define VTL 13568
#define SHI 17920   // [16][36]u16 : (4b+s)*72 + 2d
#define SLO 19072
#define UHX 20224   // [16][36]u16 (single bf16 u)
#define ATH 21376   // [4]b stride 160B, [4]s stride 32B, [16]n u16
#define ATL 22016
#define ZPG 22656   // 16B zeros

__global__ __launch_bounds__(64, 2)
void slotattn_mfma(const float* __restrict__ latent,
                   const float* __restrict__ slot_mu,
                   const float* __restrict__ w_in,
                   const float* __restrict__ b_in,
                   const float* __restrict__ ln_g,
                   const float* __restrict__ ln_b,
                   const float* __restrict__ gbih,
                   const float* __restrict__ gbhh,
                   const unsigned int* __restrict__ ws,
                   float* __restrict__ out)
{
  __shared__ __attribute__((aligned(16))) char sw[22688];
  const int l = threadIdx.x & 63;
  const int g = l >> 4;
  const int m = l & 15;
  const int batch0 = blockIdx.x * 4;

  if (l == 0){ u32x4 z = {0,0,0,0}; *(u32x4*)(sw + ZPG) = z; }

  // ---- Phase A: latent -> proj -> LN -> x hi/lo to LDS (thread = batch g, token m) ----
  {
    const float* latp = latent + (size_t)(batch0 + g) * 128 + m;
    float c[8];
    #pragma unroll
    for (int cc=0; cc<8; ++cc) c[cc] = latp[cc*16];
    float xr[32];
    #pragma unroll
    for (int d=0; d<32; ++d){
      float acc = b_in[d];
      #pragma unroll
      for (int cc=0; cc<8; ++cc) acc = fmaf(c[cc], w_in[d*8+cc], acc);
      xr[d] = acc;
    }
    float mu = 0.f;
    #pragma unroll
    for (int d=0; d<32; ++d) mu += xr[d];
    mu *= 0.03125f;
    float var = 0.f;
    #pragma unroll
    for (int d=0; d<32; ++d){ float t = xr[d]-mu; var = fmaf(t,t,var); }
    var *= 0.03125f;
    float rs = rsqrtf(var + 1e-5f);
    #pragma unroll
    for (int d=0; d<32; ++d) xr[d] = (xr[d]-mu)*rs*ln_g[d] + ln_b[d];

    unsigned int hw[16], lw[16];
    #pragma unroll
    for (int p=0; p<16; ++p) split2(xr[2*p], xr[2*p+1], hw[p], lw[p]);
    char* dsth = sw + KQH + g*1152 + m*72;
    char* dstl = sw + KQL + g*1152 + m*72;
    #pragma unroll
    for (int q=0; q<8; ++q){
      uint2 hv = { hw[2*q], hw[2*q+1] };
      uint2 lv = { lw[2*q], lw[2*q+1] };
      *(uint2*)(dsth + q*8) = hv;
      *(uint2*)(dstl + q*8) = lv;
    }
  }
  asm volatile("" ::: "memory");

  // ---- Phase C: kq = x@wfuse, v = x@wv^T ; kq -> KQ (hi/lo), v^T -> VT2 (hi/lo) ----
  {
    FragU xh[4], xl[4];
    #pragma unroll
    for (int bt=0; bt<4; ++bt){
      xh[bt].f = ldfrag(sw + KQH + bt*1152 + m*72 + 16*g);
      xl[bt].f = ldfrag(sw + KQL + bt*1152 + m*72 + 16*g);
    }
    asm volatile("" ::: "memory");
    WPair wf0 = load_pre(ws, 0, l), wf1 = load_pre(ws, 1, l);
    WPair wv0 = load_pre(ws, 2, l), wv1 = load_pre(ws, 3, l);
    #pragma unroll
    for (int bt=0; bt<4; ++bt){
      f32x4 z = {0,0,0,0};
      f32x4 k0 = mfma3(xh[bt].f, xl[bt].f, wf0.h, wf0.l, z);
      f32x4 k1 = mfma3(xh[bt].f, xl[bt].f, wf1.h, wf1.l, z);
      f32x4 v0 = mfma3(xh[bt].f, xl[bt].f, wv0.h, wv0.l, z);
      f32x4 v1 = mfma3(xh[bt].f, xl[bt].f, wv1.h, wv1.l, z);
      unsigned short vh0[4], vl0[4], vh1[4], vl1[4];
      #pragma unroll
      for (int r=0; r<4; ++r){
        int tok = 4*g + r;
        unsigned short h0,l0,h1,l1;
        trsplit(k0[r], h0, l0);
        trsplit(k1[r], h1, l1);
        *(unsigned short*)(sw + KQH + bt*1152 + tok*72 + 2*m)      = h0;
        *(unsigned short*)(sw + KQL + bt*1152 + tok*72 + 2*m)      = l0;
        *(unsigned short*)(sw + KQH + bt*1152 + tok*72 + 2*(m+16)) = h1;
        *(unsigned short*)(sw + KQL + bt*1152 + tok*72 + 2*(m+16)) = l1;
        trsplit(v0[r], vh0[r], vl0[r]);
        trsplit(v1[r], vh1[r], vl1[r]);
      }
      uint2 ph0 = { (unsigned)vh0[0]|((unsigned)vh0[1]<<16), (unsigned)vh0[2]|((unsigned)vh0[3]<<16) };
      uint2 pl0 = { (unsigned)vl0[0]|((unsigned)vl0[1]<<16), (unsigned)vl0[2]|((unsigned)vl0[3]<<16) };
      uint2 ph1 = { (unsigned)vh1[0]|((unsigned)vh1[1]<<16), (unsigned)vh1[2]|((unsigned)vh1[3]<<16) };
      uint2 pl1 = { (unsigned)vl1[0]|((unsigned)vl1[1]<<16), (unsigned)vl1[2]|((unsigned)vl1[3]<<16) };
      int cbase = 2*(bt*16 + 4*g);
      *(uint2*)(sw + VTH + m*136      + cbase) = ph0;
      *(uint2*)(sw + VTL + m*136      + cbase) = pl0;
      *(uint2*)(sw + VTH + (m+16)*136 + cbase) = ph1;
      *(uint2*)(sw + VTL + (m+16)*136 + cbase) = pl1;
    }
  }

  // ---- h init: fp32 in registers + bf16 hi/lo fragments to LDS ----
  float hreg[8];   // hreg[4T+r] = h[(b=g, s=r)][d = m+16T]
  #pragma unroll
  for (int T=0; T<2; ++T){
    #pragma unroll
    for (int r=0; r<4; ++r){
      float v = slot_mu[r*32 + m + 16*T];
      hreg[4*T+r] = v;
      unsigned short h, lo;
      split1(v, h, lo);
      *(unsigned short*)(sw + SHI + (4*g+r)*72 + 2*(m+16*T)) = h;
      *(unsigned short*)(sw + SLO + (4*g+r)*72 + 2*(m+16*T)) = lo;
    }
  }

  // ---- persistent GRU weight fragments + biases ----
  WPair wihf[6], whhf[6];
  float bihl[6], bhhl[6];
  #pragma unroll
  for (int t=0; t<6; ++t){
    wihf[t] = load_pre(ws, 4+t, l);
    whhf[t] = load_pre(ws, 10+t, l);
    bihl[t] = gbih[t*16 + m];
    bhhl[t] = gbhh[t*16 + m];
  }

  for (int it=0; it<3; ++it){
    asm volatile("" ::: "memory");
    FragU sh, sl;
    sh.f = ldfrag(sw + SHI + m*72 + 16*g);
    sl.f = ldfrag(sw + SLO + m*72 + 16*g);

    // logits = slots @ kq^T per batch; lane keeps batch g (rows 4g+r = slot r)
    f32x4 ls = {0,0,0,0};
    #pragma unroll
    for (int bt=0; bt<4; ++bt){
      bf16x8 bh = ldfrag(sw + KQH + bt*1152 + m*72 + 16*g);
      bf16x8 bl = ldfrag(sw + KQL + bt*1152 + m*72 + 16*g);
      f32x4 z = {0,0,0,0};
      f32x4 la = mfma3(sh.f, sl.f, bh, bl, z);
      if (bt==0) ls = la;
      else {
        bool take = (g==bt);
        #pragma unroll
        for (int c2=0;c2<4;++c2) ls[c2] = take ? la[c2] : ls[c2];
      }
    }
    // softmax over slots (batch g, token m) -> attn bf16 hi/lo to LDS
    {
      float mx = fmaxf(fmaxf(ls[0],ls[1]), fmaxf(ls[2],ls[3]));
      float e0=__expf(ls[0]-mx), e1=__expf(ls[1]-mx), e2=__expf(ls[2]-mx), e3=__expf(ls[3]-mx);
      float inv = 1.f/(e0+e1+e2+e3);
      float ev[4] = { e0*inv, e1*inv, e2*inv, e3*inv };
      #pragma unroll
      for (int s=0; s<4; ++s){
        unsigned short h, lo;
        trsplit(ev[s], h, lo);
        *(unsigned short*)(sw + ATH + g*160 + s*32 + 2*m) = h;
        *(unsigned short*)(sw + ATL + g*160 + s*32 + 2*m) = lo;
      }
    }
    asm volatile("" ::: "memory");

    // updates^T = v^T @ attn^T : D[row=d][col=(b,s)], 2 batches per MFMA via K=32
    FragU abh[2], abl[2];
    #pragma unroll
    for (int inst=0; inst<2; ++inst){
      bool match = ((m>>2) == inst*2 + (g>>1));
      int aoff = (m>>2)*160 + (m&3)*32 + (g&1)*16;
      const char* pH = match ? (sw + ATH + aoff) : (sw + ZPG);
      const char* pL = match ? (sw + ATL + aoff) : (sw + ZPG);
      abh[inst].u4 = *(const u32x4*)pH;
      abl[inst].u4 = *(const u32x4*)pL;
    }
    f32x4 uT[2];
    #pragma unroll
    for (int T=0; T<2; ++T){
      f32x4 acc = {0,0,0,0};
      #pragma unroll
      for (int inst=0; inst<2; ++inst){
        int bk = inst*2 + (g>>1);
        int voff = (16*T + m)*136 + bk*32 + (g&1)*16;
        bf16x8 vah = ldfrag(sw + VTH + voff);
        bf16x8 val = ldfrag(sw + VTL + voff);
        acc = mfma3(vah, val, abh[inst].f, abl[inst].f, acc);
      }
      uT[T] = acc;
    }
    // u write: lane holds upd[(b,s)=m][d=16T+4g+r] -> single bf16
    #pragma unroll
    for (int T=0; T<2; ++T){
      unsigned short q0=rne1(uT[T][0]), q1=rne1(uT[T][1]), q2=rne1(uT[T][2]), q3=rne1(uT[T][3]);
      uint2 pw = { (unsigned)q0|((unsigned)q1<<16), (unsigned)q2|((unsigned)q3<<16) };
      *(uint2*)(sw + UHX + m*72 + 32*T + 8*g) = pw;
    }
    asm volatile("" ::: "memory");

    // GRU: gi = u@wih^T + bih (2-term); gh = h@whh^T + bhh (3-term)
    bf16x8 uh = ldfrag(sw + UHX + m*72 + 16*g);
    f32x4 gi[6], gh[6];
    #pragma unroll
    for (int t=0;t<6;++t){
      f32x4 ci = { bihl[t], bihl[t], bihl[t], bihl[t] };
      gi[t] = mfma2(uh, wihf[t].h, wihf[t].l, ci);
      f32x4 ch = { bhhl[t], bhhl[t], bhhl[t], bhhl[t] };
      gh[t] = mfma3(sh.f, sl.f, whhf[t].h, whhf[t].l, ch);
    }
    bool last = (it==2);
    #pragma unroll
    for (int T=0;T<2;++T){
      #pragma unroll
      for (int r=0;r<4;++r){
        float ir=gi[T][r], iz=gi[2+T][r], inn=gi[4+T][r];
        float hr=gh[T][r], hz=gh[2+T][r], hn=gh[4+T][r];
        float rr = 1.f/(1.f+__expf(-(ir+hr)));
        float zz = 1.f/(1.f+__expf(-(iz+hz)));
        float pre = inn + rr*hn;
        float nn = 1.f - 2.f/(__expf(2.f*pre)+1.f);
        int d = m + 16*T;
        float hval = hreg[4*T+r];
        float hnew = nn + zz*(hval-nn);
        hreg[4*T+r] = hnew;
        if (last){
          out[(size_t)(batch0+g)*128 + r*32 + d] = hnew;
        } else {
          unsigned short h2,l2;
          trsplit(hnew,h2,l2);
          *(unsigned short*)(sw + SHI + (4*g+r)*72 + 2*d) = h2;
          *(unsigned short*)(sw + SLO + (4*g+r)*72 + 2*d) = l2;
        }
      }
    }
  }
}

extern "C" void kernel_launch(void* const* d_in, const int* in_sizes, int n_in,
                              void* d_out, int out_size, void* d_ws, size_t ws_size,
                              hipStream_t stream) {
  const float* latent  = (const float*)d_in[0];
  const float* slot_mu = (const float*)d_in[1];
  const float* w_in    = (const float*)d_in[2];
  const float* b_in    = (const float*)d_in[3];
  const float* ln_g    = (const float*)d_in[4];
  const float* ln_b    = (const float*)d_in[5];
  const float* wq      = (const float*)d_in[6];
  const float* wk      = (const float*)d_in[7];
  const float* wv      = (const float*)d_in[8];
  const float* gwih    = (const float*)d_in[9];
  const float* gwhh    = (const float*)d_in[10];
  const float* gbih    = (const float*)d_in[11];
  const float* gbhh    = (const float*)d_in[12];
  float* out = (float*)d_out;
  unsigned int* ws = (unsigned int*)d_ws;

  prep_kernel<<<1, 64, 0, stream>>>(wq, wk, wv, gwih, gwhh, ws);

  const int B = in_sizes[0] >> 7;    // 65536
  const int grid = B >> 2;           // 16384 blocks x 64 threads (1 wave, 4 batches)
  slotattn_mfma<<<grid, 64, 0, stream>>>(latent, slot_mu, w_in, b_in, ln_g, ln_b,
                                         gbih, gbhh, ws, out);
}

// Round 6
// 156.394 us; speedup vs baseline: 6.8840x; 1.0355x over previous
//
#include <hip/hip_runtime.h>

typedef short bf16x8 __attribute__((ext_vector_type(8)));
typedef float f32x4  __attribute__((ext_vector_type(4)));
typedef unsigned int u32x4 __attribute__((ext_vector_type(4)));

#define MFMA16(a,b,c) __builtin_amdgcn_mfma_f32_16x16x32_bf16(a,b,c,0,0,0)
#define SCALE_F 0.17677669529663687f

union FragU { u32x4 u4; unsigned int u[4]; bf16x8 f; };
struct WPair { bf16x8 h, l; };

__device__ __forceinline__ unsigned short rne1(float x){
  unsigned int u = __float_as_uint(x);
  return (unsigned short)((u + 0x7fffu + ((u>>16)&1u)) >> 16);
}
__device__ __forceinline__ void split1(float x, unsigned short& h, unsigned short& l){
  h = rne1(x);
  float hf = __uint_as_float((unsigned)h<<16);
  l = rne1(x - hf);
}
// packed hi/lo u32: [31:16] = truncated-hi bf16, [15:0] = bf16(residual)
__device__ __forceinline__ unsigned int pk32(float x){
  unsigned int u = __float_as_uint(x);
  unsigned int h = u & 0xffff0000u;
  float r = x - __uint_as_float(h);
  return h | (__float_as_uint(r) >> 16);
}
// 8 packed u32 (consecutive k-elems) -> hi frag + lo frag
__device__ __forceinline__ void unpack8(const unsigned int* ur, FragU& hi, FragU& lo){
  #pragma unroll
  for (int i=0;i<4;++i){
    hi.u[i] = __builtin_amdgcn_perm(ur[2*i+1], ur[2*i], 0x07060302u);
    lo.u[i] = __builtin_amdgcn_perm(ur[2*i+1], ur[2*i], 0x05040100u);
  }
}
__device__ __forceinline__ f32x4 mfma3(bf16x8 ah, bf16x8 al, bf16x8 bh, bf16x8 bl, f32x4 c){
  c = MFMA16(ah, bh, c);
  c = MFMA16(al, bh, c);
  c = MFMA16(ah, bl, c);
  return c;
}

// ws: frag(t,l) at (t*64+l)*8 u32: 4 hi, 4 lo. tiles 0-1 wfuseT, 2-3 wv, 4-9 gwih, 10-15 gwhh.
__device__ __forceinline__ void store_frag(unsigned int* ws, int t, int l, const float* v){
  FragU hh, ll;
  #pragma unroll
  for (int i=0;i<4;++i){
    unsigned short h0,l0,h1,l1;
    split1(v[2*i],   h0, l0);
    split1(v[2*i+1], h1, l1);
    hh.u[i] = (unsigned)h0 | ((unsigned)h1<<16);
    ll.u[i] = (unsigned)l0 | ((unsigned)l1<<16);
  }
  *(u32x4*)(ws + (size_t)(t*64+l)*8)     = hh.u4;
  *(u32x4*)(ws + (size_t)(t*64+l)*8 + 4) = ll.u4;
}
__device__ __forceinline__ WPair load_pre(const unsigned int* ws, int t, int l){
  const unsigned int* p = ws + (size_t)(t*64+l)*8;
  FragU a,b; a.u4 = *(const u32x4*)p; b.u4 = *(const u32x4*)(p+4);
  WPair r; r.h = a.f; r.l = b.f; return r;
}

__global__ void prep_kernel(const float* __restrict__ wq,
                            const float* __restrict__ wk,
                            const float* __restrict__ wv,
                            const float* __restrict__ gwih,
                            const float* __restrict__ gwhh,
                            unsigned int* __restrict__ ws)
{
  const int l = threadIdx.x & 63;
  const int g = l >> 4, m = l & 15;
  float v[8];
  #pragma unroll
  for (int t=0; t<2; ++t){
    #pragma unroll
    for (int j=0;j<8;++j){
      int d = t*16+m, c = 8*g+j;
      float acc = 0.f;
      for (int dp=0; dp<32; ++dp) acc = fmaf(wq[dp*32+d], wk[dp*32+c], acc);
      v[j] = acc * SCALE_F;
    }
    store_frag(ws, t, l, v);
  }
  #pragma unroll
  for (int tt=0; tt<2; ++tt){
    #pragma unroll
    for (int j=0;j<8;++j) v[j] = wv[(tt*16+m)*32 + 8*g + j];
    store_frag(ws, 2+tt, l, v);
  }
  for (int tt=0; tt<6; ++tt){
    #pragma unroll
    for (int j=0;j<8;++j) v[j] = gwih[(tt*16+m)*32 + 8*g + j];
    store_frag(ws, 4+tt, l, v);
  }
  for (int tt=0; tt<6; ++tt){
    #pragma unroll
    for (int j=0;j<8;++j) v[j] = gwhh[(tt*16+m)*32 + 8*g + j];
    store_frag(ws, 10+tt, l, v);
  }
}

// LDS map (16384 B / block, 1 wave):
//  R0 @0 (8192): phases A/C: x then kq, packed u32 [4 bt][16 tok][128B]: bt*2048+tok*128+4d, XOR((tok&7)<<4)
//                iters: S @0 [16 row][128B] (row=4b+s), U @2048 same, AT @4096 [4b][4s][16n]u32, ZPG @5120 (32B)
//  VT @8192 (8192): [32 d][256B]: d*256 + 4*(bt*16+tok), XOR((d&7)<<4)
#define UOF 2048
#define ATO 4096
#define ZPGO 5120
#define VTO 8192

__global__ __launch_bounds__(64, 2)
void slotattn_mfma(const float* __restrict__ latent,
                   const float* __restrict__ slot_mu,
                   const float* __restrict__ w_in,
                   const float* __restrict__ b_in,
                   const float* __restrict__ ln_g,
                   const float* __restrict__ ln_b,
                   const float* __restrict__ gbih,
                   const float* __restrict__ gbhh,
                   const unsigned int* __restrict__ ws,
                   float* __restrict__ out)
{
  __shared__ __attribute__((aligned(16))) char sw[16384];
  const int l = threadIdx.x & 63;
  const int g = l >> 4;
  const int m = l & 15;
  const int batch0 = blockIdx.x * 4;
  const int xorm = (m & 7) << 4;

  // ---- Phase A: latent -> proj -> LN -> packed x to LDS (thread = batch g, token m) ----
  {
    const float* latp = latent + (size_t)(batch0 + g) * 128 + m;
    float c[8];
    #pragma unroll
    for (int cc=0; cc<8; ++cc) c[cc] = latp[cc*16];
    float xr[32];
    #pragma unroll
    for (int d=0; d<32; ++d){
      float acc = b_in[d];
      #pragma unroll
      for (int cc=0; cc<8; ++cc) acc = fmaf(c[cc], w_in[d*8+cc], acc);
      xr[d] = acc;
    }
    float mu = 0.f;
    #pragma unroll
    for (int d=0; d<32; ++d) mu += xr[d];
    mu *= 0.03125f;
    float var = 0.f;
    #pragma unroll
    for (int d=0; d<32; ++d){ float t = xr[d]-mu; var = fmaf(t,t,var); }
    var *= 0.03125f;
    float rs = rsqrtf(var + 1e-5f);
    char* dst = sw + g*2048 + m*128;
    #pragma unroll
    for (int q=0; q<8; ++q){
      u32x4 pv;
      #pragma unroll
      for (int i=0;i<4;++i){
        int d = 4*q+i;
        pv[i] = pk32((xr[d]-mu)*rs*ln_g[d] + ln_b[d]);
      }
      *(u32x4*)(dst + ((q*16) ^ xorm)) = pv;
    }
  }
  asm volatile("" ::: "memory");

  // ---- Phase C: kq = x@wfuse, v = x@wv^T ; kq -> R0 (packed), v^T -> VT (packed) ----
  FragU kqh[4], kql[4];
  {
    unsigned int xr8[4][8];
    #pragma unroll
    for (int bt=0; bt<4; ++bt){
      const char* base = sw + bt*2048 + m*128;
      *(u32x4*)&xr8[bt][0] = *(const u32x4*)(base + ((g*32)    ^ xorm));
      *(u32x4*)&xr8[bt][4] = *(const u32x4*)(base + ((g*32+16) ^ xorm));
    }
    asm volatile("" ::: "memory");
    WPair wf0 = load_pre(ws, 0, l), wf1 = load_pre(ws, 1, l);
    WPair wv0 = load_pre(ws, 2, l), wv1 = load_pre(ws, 3, l);
    #pragma unroll
    for (int bt=0; bt<4; ++bt){
      FragU xh, xl; unpack8(xr8[bt], xh, xl);
      f32x4 z = {0,0,0,0};
      f32x4 k0 = mfma3(xh.f, xl.f, wf0.h, wf0.l, z);
      f32x4 k1 = mfma3(xh.f, xl.f, wf1.h, wf1.l, z);
      f32x4 v0 = mfma3(xh.f, xl.f, wv0.h, wv0.l, z);
      f32x4 v1 = mfma3(xh.f, xl.f, wv1.h, wv1.l, z);
      #pragma unroll
      for (int r=0; r<4; ++r){
        int row = 4*g + r;
        int xr_ = (row & 7) << 4;
        char* kb = sw + bt*2048 + row*128;
        *(unsigned int*)(kb + ((4*m)      ^ xr_)) = pk32(k0[r]);
        *(unsigned int*)(kb + ((4*(m+16)) ^ xr_)) = pk32(k1[r]);
      }
      u32x4 pv0, pv1;
      #pragma unroll
      for (int r=0;r<4;++r){ pv0[r] = pk32(v0[r]); pv1[r] = pk32(v1[r]); }
      *(u32x4*)(sw + VTO + m*256      + ((bt*64 + 16*g) ^ xorm)) = pv0;
      *(u32x4*)(sw + VTO + (m+16)*256 + ((bt*64 + 16*g) ^ xorm)) = pv1;
    }
    asm volatile("" ::: "memory");
    // one-time kq B-frags -> registers
    #pragma unroll
    for (int bt=0; bt<4; ++bt){
      const char* base = sw + bt*2048 + m*128;
      unsigned int kr[8];
      *(u32x4*)&kr[0] = *(const u32x4*)(base + ((g*32)    ^ xorm));
      *(u32x4*)&kr[4] = *(const u32x4*)(base + ((g*32+16) ^ xorm));
      unpack8(kr, kqh[bt], kql[bt]);
    }
  }
  asm volatile("" ::: "memory");

  // ---- zero page + h init (R0 region now free) ----
  if (l < 2){ u32x4 z = {0,0,0,0}; *(u32x4*)(sw + ZPGO + l*16) = z; }
  float hreg[8];   // hreg[4T+r] = h[(b=g,s=r)][d=m+16T]
  #pragma unroll
  for (int T=0; T<2; ++T){
    #pragma unroll
    for (int r=0; r<4; ++r){
      float v = slot_mu[r*32 + m + 16*T];
      hreg[4*T+r] = v;
      int row = 4*g + r;
      *(unsigned int*)(sw + row*128 + ((4*(m+16*T)) ^ ((row&7)<<4))) = pk32(v);
    }
  }

  // ---- persistent GRU weight fragments + biases ----
  WPair wihf[6], whhf[6];
  float bihl[6], bhhl[6];
  #pragma unroll
  for (int t=0; t<6; ++t){
    wihf[t] = load_pre(ws, 4+t, l);
    whhf[t] = load_pre(ws, 10+t, l);
    bihl[t] = gbih[t*16 + m];
    bhhl[t] = gbhh[t*16 + m];
  }

  for (int it=0; it<3; ++it){
    asm volatile("" ::: "memory");
    // slots A-frags
    unsigned int sr[8];
    {
      const char* sb = sw + m*128;
      *(u32x4*)&sr[0] = *(const u32x4*)(sb + ((g*32)    ^ xorm));
      *(u32x4*)&sr[4] = *(const u32x4*)(sb + ((g*32+16) ^ xorm));
    }
    FragU sh, sl; unpack8(sr, sh, sl);

    // logits = slots @ kq^T (kq frags in regs); keep batch g
    f32x4 ls = {0,0,0,0};
    #pragma unroll
    for (int bt=0; bt<4; ++bt){
      f32x4 z = {0,0,0,0};
      f32x4 la = mfma3(sh.f, sl.f, kqh[bt].f, kql[bt].f, z);
      if (bt==0) ls = la;
      else {
        bool take = (g==bt);
        #pragma unroll
        for (int c2=0;c2<4;++c2) ls[c2] = take ? la[c2] : ls[c2];
      }
    }
    // softmax over slots (batch g, token m) -> packed AT
    {
      float mx = fmaxf(fmaxf(ls[0],ls[1]), fmaxf(ls[2],ls[3]));
      float e0=__expf(ls[0]-mx), e1=__expf(ls[1]-mx), e2=__expf(ls[2]-mx), e3=__expf(ls[3]-mx);
      float inv = 1.f/(e0+e1+e2+e3);
      float ev[4] = { e0*inv, e1*inv, e2*inv, e3*inv };
      #pragma unroll
      for (int s=0; s<4; ++s)
        *(unsigned int*)(sw + ATO + g*256 + s*64 + 4*m) = pk32(ev[s]);
    }
    asm volatile("" ::: "memory");

    // updates^T = v^T @ attn^T : 2 batches packed per MFMA (K=32)
    FragU abh[2], abl[2];
    #pragma unroll
    for (int inst=0; inst<2; ++inst){
      bool match = ((m>>2) == inst*2 + (g>>1));
      const char* ap = match ? (sw + ATO + (m>>2)*256 + (m&3)*64 + (g&1)*32)
                             : (sw + ZPGO);
      unsigned int ar[8];
      *(u32x4*)&ar[0] = *(const u32x4*)ap;
      *(u32x4*)&ar[4] = *(const u32x4*)(ap + 16);
      unpack8(ar, abh[inst], abl[inst]);
    }
    f32x4 uT[2];
    #pragma unroll
    for (int T=0; T<2; ++T){
      f32x4 acc = {0,0,0,0};
      #pragma unroll
      for (int inst=0; inst<2; ++inst){
        int bk = inst*2 + (g>>1);
        const char* vb = sw + VTO + (16*T+m)*256;
        unsigned int vr[8];
        *(u32x4*)&vr[0] = *(const u32x4*)(vb + ((bk*64 + (g&1)*32)      ^ xorm));
        *(u32x4*)&vr[4] = *(const u32x4*)(vb + ((bk*64 + (g&1)*32 + 16) ^ xorm));
        FragU vah, val; unpack8(vr, vah, val);
        acc = mfma3(vah.f, val.f, abh[inst].f, abl[inst].f, acc);
      }
      uT[T] = acc;
    }
    // u writeback: lane holds upd[(b,s)=m][d=16T+4g+r] -> packed u32, b128
    #pragma unroll
    for (int T=0; T<2; ++T){
      u32x4 up;
      #pragma unroll
      for (int r=0;r<4;++r) up[r] = pk32(uT[T][r]);
      *(u32x4*)(sw + UOF + m*128 + ((64*T + 16*g) ^ xorm)) = up;
    }
    asm volatile("" ::: "memory");

    // u A-frags
    unsigned int ur2[8];
    {
      const char* ub = sw + UOF + m*128;
      *(u32x4*)&ur2[0] = *(const u32x4*)(ub + ((g*32)    ^ xorm));
      *(u32x4*)&ur2[4] = *(const u32x4*)(ub + ((g*32+16) ^ xorm));
    }
    FragU uh, ul; unpack8(ur2, uh, ul);

    // GRU per output half T (tiles t = {T, 2+T, 4+T}) to limit acc pressure
    bool last = (it==2);
    #pragma unroll
    for (int T=0; T<2; ++T){
      f32x4 gi3[3], gh3[3];
      #pragma unroll
      for (int s3=0; s3<3; ++s3){
        int t = 2*s3 + T;
        f32x4 ci = { bihl[t], bihl[t], bihl[t], bihl[t] };
        gi3[s3] = mfma3(uh.f, ul.f, wihf[t].h, wihf[t].l, ci);
        f32x4 ch = { bhhl[t], bhhl[t], bhhl[t], bhhl[t] };
        gh3[s3] = mfma3(sh.f, sl.f, whhf[t].h, whhf[t].l, ch);
      }
      #pragma unroll
      for (int r=0; r<4; ++r){
        float ir=gi3[0][r], iz=gi3[1][r], inn=gi3[2][r];
        float hr=gh3[0][r], hz=gh3[1][r], hn=gh3[2][r];
        float rr = 1.f/(1.f+__expf(-(ir+hr)));
        float zz = 1.f/(1.f+__expf(-(iz+hz)));
        float pre = inn + rr*hn;
        float nn = 1.f - 2.f/(__expf(2.f*pre)+1.f);
        int d = m + 16*T;
        float hval = hreg[4*T+r];
        float hnew = nn + zz*(hval-nn);
        hreg[4*T+r] = hnew;
        if (last){
          out[(size_t)(batch0+g)*128 + r*32 + d] = hnew;
        } else {
          int row = 4*g + r;
          *(unsigned int*)(sw + row*128 + ((4*d) ^ ((row&7)<<4))) = pk32(hnew);
        }
      }
    }
  }
}

extern "C" void kernel_launch(void* const* d_in, const int* in_sizes, int n_in,
                              void* d_out, int out_size, void* d_ws, size_t ws_size,
                              hipStream_t stream) {
  const float* latent  = (const float*)d_in[0];
  const float* slot_mu = (const float*)d_in[1];
  const float* w_in    = (const float*)d_in[2];
  const float* b_in    = (const float*)d_in[3];
  const float* ln_g    = (const float*)d_in[4];
  const float* ln_b    = (const float*)d_in[5];
  const float* wq      = (const float*)d_in[6];
  const float* wk      = (const float*)d_in[7];
  const float* wv      = (const float*)d_in[8];
  const float* gwih    = (const float*)d_in[9];
  const float* gwhh    = (const float*)d_in[10];
  const float* gbih    = (const float*)d_in[11];
  const float* gbhh    = (const float*)d_in[12];
  float* out = (float*)d_out;
  unsigned int* ws = (unsigned int*)d_ws;

  prep_kernel<<<1, 64, 0, stream>>>(wq, wk, wv, gwih, gwhh, ws);

  const int B = in_sizes[0] >> 7;    // 65536
  const int grid = B >> 2;           // 16384 blocks x 64 threads (1 wave, 4 batches)
  slotattn_mfma<<<grid, 64, 0, stream>>>(latent, slot_mu, w_in, b_in, ln_g, ln_b,
                                         gbih, gbhh, ws, out);
}